// Round 1
// baseline (830.973 us; speedup 1.0000x reference)
//
#include <hip/hip_runtime.h>

// Fp8Padding: multi-segment row copy with 16-row-aligned zero padding.
// M_SPLITS = [8191,8190,8185,8200,8100,8216,8177,8193] (static per reference)
// padded   = [8192,8192,8192,8208,8112,8224,8192,8208], total out rows 65520
// IN_FEATURES = 2048 fp32 -> 512 float4 per row.

#define N_SEG 8
#define ROW_F4 512            // 2048 floats / 4
#define OUT_ROWS 65520

__global__ __launch_bounds__(256) void pad_copy_kernel(
    const float4* __restrict__ inp, float4* __restrict__ out) {
    // Compile-time segment tables.
    const int cum_pad[N_SEG + 1] = {0, 8192, 16384, 24576, 32784, 40896, 49120, 57312, 65520};
    const int cum_in[N_SEG]      = {0, 8191, 16381, 24566, 32766, 40866, 49082, 57259};
    const int mseg[N_SEG]        = {8191, 8190, 8185, 8200, 8100, 8216, 8177, 8193};

    const int row = blockIdx.x;          // one block per padded output row
    const int tid = threadIdx.x;         // 256 threads, 2 float4 each

    // Wave-uniform segment lookup (7 scalar compares).
    int seg = 0;
#pragma unroll
    for (int i = 1; i < N_SEG; ++i) seg += (row >= cum_pad[i]);

    const int j = row - cum_pad[seg];    // row within segment
    const bool valid = (j < mseg[seg]);  // uniform across the block

    float4* orow = out + (size_t)row * ROW_F4;

    if (valid) {
        const float4* irow = inp + (size_t)(cum_in[seg] + j) * ROW_F4;
        orow[tid]       = irow[tid];
        orow[tid + 256] = irow[tid + 256];
    } else {
        const float4 z = make_float4(0.f, 0.f, 0.f, 0.f);
        orow[tid]       = z;
        orow[tid + 256] = z;
    }
}

extern "C" void kernel_launch(void* const* d_in, const int* in_sizes, int n_in,
                              void* d_out, int out_size, void* d_ws, size_t ws_size,
                              hipStream_t stream) {
    const float4* inp = (const float4*)d_in[0];   // (65452, 2048) fp32
    float4* out = (float4*)d_out;                 // (65520, 2048) fp32
    (void)in_sizes; (void)n_in; (void)d_ws; (void)ws_size; (void)out_size;

    pad_copy_kernel<<<OUT_ROWS, 256, 0, stream>>>(inp, out);
}